// Round 6
// baseline (404.584 us; speedup 1.0000x reference)
//
#include <hip/hip_runtime.h>
#include <hip/hip_bf16.h>
#include <math.h>

#define EPS_BN 1e-5f

typedef __bf16 bf16x8 __attribute__((ext_vector_type(8)));
typedef float f32x4 __attribute__((ext_vector_type(4)));
typedef float f32x2 __attribute__((ext_vector_type(2)));

// async global->LDS, 16B per lane. LDS dest must be wave-uniform base + lane*16
__device__ __forceinline__ void gl2lds16(const void* g, void* l) {
  __builtin_amdgcn_global_load_lds(
      (const __attribute__((address_space(1))) unsigned int*)g,
      (__attribute__((address_space(3))) unsigned int*)l, 16, 0, 0);
}

// ============================================================================
// R18 FUSED conv1 + weight-prep (one launch; all block ranges independent):
//   blocks [0,1152):            conv2 w -> bf16 [9][8][128][4][8]
//   blocks [1152,1440):         conv3 w -> bf16 [9][16][64][8]
//   blocks [1440,1568):         W32 = att_w[64,256] @ fc2_w[256,512]
//   block  1568:                b_eff = att_w@(fc2_w@fc1_b + fc2_b) + att_b
//   blocks [nprep, nprep+CH*4): conv1 band path -> out1p bf16 NHWC [26][26][256]
// (W_eff moved to k_mconv2's launch — it needs W32 from THIS launch.)
// Fusion rationale (R18): NCHK=1 discovered via WRITE_SIZE=512*36864 exactly;
// per-iteration tail ~257us is dominated by serialized small kernels + harness
// resets. prep is independent of conv1 bands -> same grid, zero serial cost.
// ============================================================================
__global__ __launch_bounds__(256) void k_conv1prep(
    const float* __restrict__ x, const float* __restrict__ w,
    const float* __restrict__ cb, const float* __restrict__ g,
    const float* __restrict__ bb, const float* __restrict__ m,
    const float* __restrict__ v, __hip_bfloat16* __restrict__ out1p,
    __hip_bfloat16* __restrict__ out2p, const float* __restrict__ c2w,
    __hip_bfloat16* __restrict__ wt2, const float* __restrict__ c3w,
    __hip_bfloat16* __restrict__ wt3, const float* __restrict__ attw,
    const float* __restrict__ fc2w, float* __restrict__ W32,
    const float* __restrict__ fc1b, const float* __restrict__ fc2b,
    const float* __restrict__ attb, float* __restrict__ be, int nprep) {
  __shared__ float xp[14 * 50];
  const int blk = blockIdx.x;
  const int t = threadIdx.x;
  if (blk < nprep) {  // ---- weight prep paths (chunk 0 only) ----
    if (blk < 1152) {  // conv2 wt: [9][8][128][4][8]
      int idx = blk * 256 + t;
      int icr = idx & 7;
      int lhi = (idx >> 3) & 3;
      int oc = (idx >> 5) & 127;
      int rest = idx >> 12;
      int kb = rest & 7;
      int p = rest >> 3;
      int ic = kb * 32 + lhi * 8 + icr;
      wt2[idx] = __float2bfloat16(c2w[(oc * 256 + ic) * 9 + p]);
    } else if (blk < 1440) {  // conv3 wt: [9][16][64][8]
      int idx = (blk - 1152) * 256 + t;
      int icr = idx & 7;
      int oc = (idx >> 3) & 63;
      int rest = idx >> 9;
      int icg = rest & 15;
      int p = rest >> 4;
      wt3[idx] = __float2bfloat16(c3w[(oc * 128 + icg * 8 + icr) * 9 + p]);
    } else if (blk < 1568) {  // W32 = att_w @ fc2_w
      int idx = (blk - 1440) * 256 + t;
      int r = idx >> 9, c = idx & 511;
      float s = 0.f;
      for (int k = 0; k < 256; k++)
        s = fmaf(attw[r * 256 + k], fc2w[k * 512 + c], s);
      W32[idx] = s;
    } else {  // b_eff (t1 aliases xp's LDS)
      float* t1 = xp;
      float s = fc2b[t];
      for (int k = 0; k < 512; k++) s = fmaf(fc2w[t * 512 + k], fc1b[k], s);
      t1[t] = s;
      __syncthreads();
      if (t < 64) {
        float r = attb[t];
        for (int k = 0; k < 256; k++) r = fmaf(attw[t * 256 + k], t1[k], r);
        be[t] = r;
      }
    }
    return;
  }
  // ---- conv1 band path: band q covers output rows 6q..6q+5 ----
  const int bq = blk - nprep;
  const int b = bq >> 2, q = bq & 3;
  __hip_bfloat16* ob = out1p + (size_t)b * (26 * 26 * 256);
  const __hip_bfloat16 z = __float2bfloat16(0.f);
  if (q == 0)
    for (int i = t; i < 26 * 256; i += 256) ob[i] = z;
  if (q == 3)
    for (int i = t; i < 26 * 256; i += 256) ob[25 * 26 * 256 + i] = z;
  for (int i = t; i < 6 * 2 * 256; i += 256) {
    int r = 1 + 6 * q + (i >> 9), side = (i >> 8) & 1, c = i & 255;
    ob[(r * 26 + side * 25) * 256 + c] = z;
  }
  {
    __hip_bfloat16* o2 = out2p + (size_t)b * (14 * 14 * 128);
    if (q == 0)
      for (int i = t; i < 14 * 128; i += 256) o2[i] = z;
    if (q == 1)
      for (int i = t; i < 14 * 128; i += 256) o2[13 * 14 * 128 + i] = z;
    if (q == 2)
      for (int i = t; i < 6 * 2 * 128; i += 256) {
        int r = 1 + (i >> 8), side = (i >> 7) & 1, c = i & 127;
        o2[(r * 14 + side * 13) * 128 + c] = z;
      }
    if (q == 3)
      for (int i = t; i < 6 * 2 * 128; i += 256) {
        int r = 7 + (i >> 8), side = (i >> 7) & 1, c = i & 127;
        o2[(r * 14 + side * 13) * 128 + c] = z;
      }
  }
  for (int i = t; i < 14 * 50; i += 256) xp[i] = 0.f;
  __syncthreads();
  const float* xb = x + (size_t)b * 2304;
  for (int i = t; i < 14 * 48; i += 256) {
    int rr = i / 48, c = i - rr * 48;
    int gr = 12 * q - 1 + rr;
    if (gr >= 0 && gr < 48) xp[rr * 50 + c + 1] = xb[gr * 48 + c];
  }
  __syncthreads();
  float wr[9];
#pragma unroll
  for (int i = 0; i < 9; i++) wr[i] = w[t * 9 + i];
  const float scale = g[t] * rsqrtf(v[t] + EPS_BN);
  const float bias = (cb[t] - m[t]) * scale + bb[t];
#pragma unroll
  for (int ohl = 0; ohl < 6; ohl++) {
    const int r0 = 2 * ohl;
    f32x2 c01[4];
#pragma unroll
    for (int r = 0; r < 4; r++) c01[r] = *(const f32x2*)&xp[(r0 + r) * 50];
#pragma unroll 4
    for (int ow = 0; ow < 24; ow++) {
      f32x2 c23[4];
#pragma unroll
      for (int r = 0; r < 4; r++)
        c23[r] = *(const f32x2*)&xp[(r0 + r) * 50 + 2 * ow + 2];
      f32x2 s2a = 0.f, s2b = 0.f;  // dh = 0, 1 (packed over dw)
#pragma unroll
      for (int r = 0; r < 4; r++) {
        f32x2 p0 = c01[r], p2 = c23[r];
        f32x2 p1 = {p0.y, p2.x};
        if (r <= 2) {
          s2a += p0 * wr[r * 3 + 0];
          s2a += p1 * wr[r * 3 + 1];
          s2a += p2 * wr[r * 3 + 2];
        }
        if (r >= 1) {
          s2b += p0 * wr[(r - 1) * 3 + 0];
          s2b += p1 * wr[(r - 1) * 3 + 1];
          s2b += p2 * wr[(r - 1) * 3 + 2];
        }
      }
      f32x2 b0 = s2a * scale + bias;  // BN before pool
      f32x2 b1 = s2b * scale + bias;
      float mx = fmaxf(fmaxf(b0.x, b0.y), fmaxf(b1.x, b1.y));
      ob[((6 * q + ohl + 1) * 26 + (ow + 1)) * 256 + t] =
          __float2bfloat16(fmaxf(mx, 0.f));
#pragma unroll
      for (int r = 0; r < 4; r++) c01[r] = c23[r];
    }
  }
}

// ============================================================================
// conv2 MFMA implicit-GEMM + BN + ReLU + pool (bf16, fp32 acc)
// + FUSED W_eff tail blocks (R18): blocks >= n2 compute
//   W_eff = W32 @ fc1_w stored transposed [2304][64] (needs W32 from launch 1;
//   they dispatch last -> overlap mconv2's drain, complementary pipes).
// Core K-loop = R17 (measured best: 146us, 57% of bf16 µbench ceiling at
// NCHK=1): A-reg ring, D=3 B-ring, precomputed A addrs, setprio around MFMA,
// 64-ic LDS dbuf via global_load_lds, late DMA (t=13), XCD swizzle over n2.
// R18 micro: abase[2][3][3] precomputes BOTH ks variants (kills the ^64 VALU
// op on odd steps; +9 VGPR, budget has room at 96).
// ============================================================================
__global__ __launch_bounds__(256) void k_mconv2(
    const __hip_bfloat16* __restrict__ in, const __hip_bfloat16* __restrict__ wt,
    const float* __restrict__ cb, const float* __restrict__ gg,
    const float* __restrict__ bbv, const float* __restrict__ bm,
    const float* __restrict__ bv, __hip_bfloat16* __restrict__ outp,
    const float* __restrict__ W32, const float* __restrict__ fc1w,
    float* __restrict__ Wet, int n2) {
  constexpr int HW = 24, IC = 256, OC = 128, HP = 26, CP = 26;
  constexpr int MTW = 6;            // m-frags per wave (all waves share M=96)
  constexpr int ROWS = 4;           // output h-rows per block
  constexpr int TILES = 6;          // blocks per image
  constexpr int WN = 32;            // wave N width
  constexpr int NF = 2;             // n-frags per wave
  constexpr int NCH = 6 * CP * 8;   // 1248 16B slots per window
  constexpr int NCHP = (NCH + 255) & ~255;  // 1280
  constexpr int NLD = NCHP / 256;   // 5
  constexpr int NSTG = 4;           // kc stages
  constexpr int ABUF = NCHP * 16;   // 20480 B per window
  constexpr int KG = IC / 32;       // 8
  constexpr int EPITCH = OC + 1;
  constexpr int EBYTES = 48 * EPITCH * 4;
  constexpr int SMB = (2 * ABUF) > EBYTES ? (2 * ABUF) : EBYTES;
  constexpr int NSTEP = NSTG * 18;  // 72
  constexpr int D = 3;              // B prefetch depth (register ring)
  constexpr int AD = 3;             // A prefetch ring depth

  const int tid = threadIdx.x;
  if ((int)blockIdx.x >= n2) {  // ---- fused W_eff path ----
    int idx = ((int)blockIdx.x - n2) * 256 + tid;  // 64*2304
    int r = idx / 2304, c = idx - r * 2304;
    float s = 0.f;
    for (int k = 0; k < 512; k++)
      s = fmaf(W32[r * 512 + k], fc1w[k * 2304 + c], s);
    Wet[c * 64 + r] = s;  // transposed store
    return;
  }

  __shared__ __align__(16) char smraw[SMB];
  float* se = (float*)smraw;

  const int wn = tid >> 6, ln = tid & 63;
  const int lhi = ln >> 4, llo = ln & 15;

  // XCD-aware remap over the n2 conv blocks: all TILES tiles of an image on
  // one XCD's L2.
  const int per = n2 >> 3;
  const int xcd = blockIdx.x & 7, sl = blockIdx.x >> 3;
  const int b = xcd * (per / TILES) + sl / TILES;
  const int T = sl % TILES;
  const int h0 = T * ROWS;

  const __hip_bfloat16* inb = in + (size_t)b * HP * HP * IC;

  int srcoff[NLD];
#pragma unroll
  for (int i = 0; i < NLD; i++) {
    int ci = tid + i * 256;
    if (ci >= NCH) ci = NCH - 1;
    int kgslot = ci & 7;
    int rest = ci >> 3;
    int c = rest % CP;
    int r = rest / CP;
    int kg = kgslot ^ (c & 7);
    srcoff[i] = ((h0 + r) * HP + c) * IC + kg * 8;
  }
  // Loop-invariant A-fragment byte addrs, BOTH ks variants precomputed.
  // Full addr = abase[ks][mt%3][pw] + ph*3328 + (mt>=3)*6656 + (s&1)*20480
  // (trailing terms are compile-time imm under full unroll).
  int abase[2][3][3];
#pragma unroll
  for (int mt = 0; mt < 3; mt++) {
    int m = mt * 16 + llo;
    int hl = m / HW, wl = m % HW;
    int spb_ = (hl * CP + wl) * 8;
#pragma unroll
    for (int pw = 0; pw < 3; pw++) {
      int a0 = (spb_ + pw * 8 + (lhi ^ ((wl + pw) & 7))) * 16;
      abase[0][mt][pw] = a0;
      abase[1][mt][pw] = a0 ^ 64;  // kg bit2 -> byte addr bit6, carry-free
    }
  }
  const __hip_bfloat16* wtb = wt + (wn * WN + llo) * 32 + lhi * 8;

  f32x4 acc[MTW][NF];
  const f32x4 fz = {0.f, 0.f, 0.f, 0.f};
#pragma unroll
  for (int i = 0; i < MTW; i++)
#pragma unroll
    for (int j = 0; j < NF; j++) acc[i][j] = fz;

  // A-fragment loader for step t of window s (s,t compile-time const under
  // full unroll -> static aq indices + imm ds offsets, no scratch).
  auto LDA = [&](int s, int t, bf16x8* dst) {
    const int p = t >> 1, ks = t & 1;
    const int ph = p / 3, pw = p % 3;
    const int boff = ph * 3328 + ((s & 1) ? ABUF : 0);
#pragma unroll
    for (int mt = 0; mt < MTW; mt++) {
      dst[mt] = *(const bf16x8*)(smraw + abase[ks][mt % 3][pw] + boff +
                                 (mt >= 3 ? 6656 : 0));
    }
  };

  // prologue: DMA stage 0 into window 0; preload B ring for steps 0..D-1
#pragma unroll
  for (int i = 0; i < NLD; i++)
    gl2lds16(inb + srcoff[i], smraw + (tid + i * 256) * 16);
  bf16x8 bq[D][NF];
#pragma unroll
  for (int d = 0; d < D; d++) {
    const int sg = d / 18, pg = (d % 18) >> 1, kf = d & 1;
#pragma unroll
    for (int j = 0; j < NF; j++)
      bq[d][j] = *(const bf16x8*)(wtb +
                                  (size_t)((pg * KG + sg * 2 + kf) * OC) * 32 +
                                  j * 512);
  }
  __syncthreads();

#pragma unroll
  for (int s = 0; s < NSTG; s++) {
    bf16x8 aq[AD][MTW];  // A register ring
    LDA(s, 0, aq[0]);
    LDA(s, 1, aq[1]);
#pragma unroll
    for (int t = 0; t < 18; t++) {
      const int g = s * 18 + t;
      // prefetch step t+2's A frags before this step's MFMAs
      if (t + 2 < 18) LDA(s, t + 2, aq[(t + 2) % AD]);
      // consume aq[t%AD] x bq[g%D]; setprio favors MFMA-entering waves
      __builtin_amdgcn_s_setprio(1);
#pragma unroll
      for (int mt = 0; mt < MTW; mt++)
#pragma unroll
        for (int j = 0; j < NF; j++)
          acc[mt][j] = __builtin_amdgcn_mfma_f32_16x16x32_bf16(
              aq[t % AD][mt], bq[g % D][j], acc[mt][j], 0, 0, 0);
      __builtin_amdgcn_s_setprio(0);
      // refill B ring slot for step g+D (after consume: WAR on ring slot)
      if (g + D < NSTEP) {
        const int gf = g + D;
        const int sg = gf / 18, pg = (gf % 18) >> 1, kf = gf & 1;
#pragma unroll
        for (int j = 0; j < NF; j++)
          bq[gf % D][j] =
              *(const bf16x8*)(wtb +
                               (size_t)((pg * KG + sg * 2 + kf) * OC) * 32 +
                               j * 512);
      }
      // issue next-window DMA LATE (after this step's ring refill)
      if (t == 13 && s + 1 < NSTG) {
        char* nb = smraw + ((s + 1) & 1) * ABUF;
#pragma unroll
        for (int i = 0; i < NLD; i++)
          gl2lds16(inb + srcoff[i] + (s + 1) * 64, nb + (tid + i * 256) * 16);
      }
    }
    __syncthreads();  // window s reads done; DMA for s+1 drained
  }

  // ---- epilogue in 48-row passes: BN+ReLU -> se [48][129], pool, store
  constexpr int OHW = HW / 2;
  constexpr int NP = 1 * OHW * OC;  // pooled rows per pass = 1
#pragma unroll
  for (int pz = 0; pz < 2; pz++) {
    if (pz) __syncthreads();
#pragma unroll
    for (int j = 0; j < NF; j++) {
      int n = wn * WN + j * 16 + llo;
      float scale = gg[n] * rsqrtf(bv[n] + EPS_BN);
      float bias = (cb[n] - bm[n]) * scale + bbv[n];
#pragma unroll
      for (int mtl = 0; mtl < 3; mtl++)
#pragma unroll
        for (int r = 0; r < 4; r++) {
          int mrow = mtl * 16 + lhi * 4 + r;
          se[mrow * EPITCH + n] =
              fmaxf(acc[pz * 3 + mtl][j][r] * scale + bias, 0.f);
        }
    }
    __syncthreads();
    for (int sI = tid; sI < NP; sI += 256) {
      int n = sI % OC;
      int ow = (sI / OC) % OHW;
      int mloc = 2 * ow;
      float x0 = se[mloc * EPITCH + n];
      float x1 = se[(mloc + 1) * EPITCH + n];
      float x2 = se[(mloc + HW) * EPITCH + n];
      float x3 = se[(mloc + HW + 1) * EPITCH + n];
      float mx = fmaxf(fmaxf(x0, x1), fmaxf(x2, x3));
      int oh = (h0 >> 1) + pz;
      // padded bf16 NHWC [14][14][128], interior at +1
      outp[(((size_t)b * 14 + oh + 1) * 14 + ow + 1) * OC + n] =
          __float2bfloat16(mx);
    }
  }
}

// ============================================================================
// FUSED conv3 + BN + ReLU + pool + spatial attention + fc3. One block/image.
// (unchanged — measured good)
// ============================================================================
__global__ __launch_bounds__(256) void k_c3attn(
    const __hip_bfloat16* __restrict__ in, const __hip_bfloat16* __restrict__ wt,
    const float* __restrict__ cb, const float* __restrict__ gg,
    const float* __restrict__ bbv, const float* __restrict__ bm,
    const float* __restrict__ bv, const float* __restrict__ Wet,
    const float* __restrict__ be, const float* __restrict__ w3,
    const float* __restrict__ b3, float* __restrict__ out, int b0) {
  constexpr int HW = 12, IC = 128, OC = 64, HP = 14, CP = 14;
  constexpr int NCH = 14 * CP * 8;
  constexpr int NCHP = (NCH + 255) & ~255;
  constexpr int NLD = NCHP / 256;
  constexpr int NSTG = 2;
  constexpr int ABUF = NCHP * 16;
  constexpr int ICG = 16;
  constexpr int EPITCH = OC + 1;

  __shared__ __align__(16) char smraw[2 * ABUF];
  __shared__ float act[64 * 37];
  __shared__ float qp[4][64];
  __shared__ float ql[64], gm[64], sc[36];
  float* se = (float*)smraw;

  const int tid = threadIdx.x;
  const int wv = tid >> 6, ln = tid & 63;
  const int lhi = ln >> 4, llo = ln & 15;
  const int b = blockIdx.x;

  const __hip_bfloat16* inb = in + (size_t)b * HP * HP * IC;

  int srcoff[NLD];
#pragma unroll
  for (int i = 0; i < NLD; i++) {
    int ci = tid + i * 256;
    if (ci >= NCH) ci = NCH - 1;
    int kgslot = ci & 7;
    int rest = ci >> 3;
    int c = rest % CP;
    int r = rest / CP;
    int kg = kgslot ^ (c & 7);
    srcoff[i] = (r * HP + c) * IC + kg * 8;
  }
  int spb[9], wlv[9];
#pragma unroll
  for (int mt = 0; mt < 9; mt++) {
    int m = mt * 16 + llo;
    int hl = m / HW, wl = m % HW;
    spb[mt] = (hl * CP + wl) * 8;
    wlv[mt] = wl;
  }
  const __hip_bfloat16* wtb = wt + (size_t)(lhi * OC + wv * 16 + llo) * 8;

  f32x4 acc[9];
  const f32x4 fz = {0.f, 0.f, 0.f, 0.f};
#pragma unroll
  for (int i = 0; i < 9; i++) acc[i] = fz;

#pragma unroll
  for (int i = 0; i < NLD; i++)
    gl2lds16(inb + srcoff[i], smraw + (tid + i * 256) * 16);
  __syncthreads();

#pragma unroll
  for (int s = 0; s < NSTG; s++) {
    if (s + 1 < NSTG) {
      char* nb = smraw + ((s + 1) & 1) * ABUF;
#pragma unroll
      for (int i = 0; i < NLD; i++)
        gl2lds16(inb + srcoff[i] + (s + 1) * 64, nb + (tid + i * 256) * 16);
    }
    const char* cw = smraw + (s & 1) * ABUF;
#pragma unroll
    for (int tt = 0; tt < 18; tt++) {
      const int p = tt >> 1, ks = tt & 1;
      const int ph = p / 3, pw = p % 3;
      const int kg = ks * 4 + lhi;
      bf16x8 bf =
          *(const bf16x8*)(wtb + ((size_t)(p * ICG + s * 8 + ks * 4) * OC) * 8);
#pragma unroll
      for (int mt = 0; mt < 9; mt++) {
        int slot = spb[mt] + (ph * CP + pw) * 8 + (kg ^ ((wlv[mt] + pw) & 7));
        bf16x8 af = *(const bf16x8*)(cw + slot * 16);
        acc[mt] = __builtin_amdgcn_mfma_f32_16x16x32_bf16(af, bf, acc[mt], 0,
                                                          0, 0);
      }
    }
    __syncthreads();
  }

  {
    const int n = wv * 16 + llo;
    const float scale = gg[n] * rsqrtf(bv[n] + EPS_BN);
    const float bias = (cb[n] - bm[n]) * scale + bbv[n];
#pragma unroll
    for (int pz = 0; pz < 3; pz++) {
      if (pz) __syncthreads();
#pragma unroll
      for (int mtl = 0; mtl < 3; mtl++)
#pragma unroll
        for (int r = 0; r < 4; r++) {
          int mrow = mtl * 16 + lhi * 4 + r;
          se[mrow * EPITCH + n] =
              fmaxf(acc[pz * 3 + mtl][r] * scale + bias, 0.f);
        }
      __syncthreads();
      for (int sI = tid; sI < 2 * 6 * 64; sI += 256) {
        int nn = sI % 64;
        int ow = (sI / 64) % 6;
        int ohl = sI / (64 * 6);
        int mloc = (2 * ohl) * HW + 2 * ow;
        float x0 = se[mloc * EPITCH + nn];
        float x1 = se[(mloc + 1) * EPITCH + nn];
        float x2 = se[(mloc + HW) * EPITCH + nn];
        float x3 = se[(mloc + HW + 1) * EPITCH + nn];
        float mx = fmaxf(fmaxf(x0, x1), fmaxf(x2, x3));
        act[nn * 37 + (pz * 2 + ohl) * 6 + ow] = mx;
      }
    }
  }
  __syncthreads();

  {
    float qpv = 0.f;
    const int n = ln;
#pragma unroll 2
    for (int c2 = wv * 16; c2 < wv * 16 + 16; c2++)
      for (int hw = 0; hw < 36; hw++)
        qpv = fmaf(act[c2 * 37 + hw], Wet[(c2 * 36 + hw) * 64 + n], qpv);
    qp[wv][n] = qpv;
  }
  __syncthreads();
  if (tid < 64)
    ql[tid] = be[tid] + qp[0][tid] + qp[1][tid] + qp[2][tid] + qp[3][tid];
  __syncthreads();
  if (wv == 0) {
    float s = -INFINITY;
    if (ln < 36) {
      float a = 0.f;
      for (int c = 0; c < 64; c++) a = fmaf(act[c * 37 + ln], ql[c], a);
      s = a;
    }
    float mx = s;
    for (int off = 32; off >= 1; off >>= 1)
      mx = fmaxf(mx, __shfl_xor(mx, off));
    float e = (ln < 36) ? expf(s - mx) : 0.f;
    float sum = e;
    for (int off = 32; off >= 1; off >>= 1) sum += __shfl_xor(sum, off);
    if (ln < 36) sc[ln] = e / sum;
  }
  __syncthreads();
  if (wv == 0) {
    float gv = 0.f;
    for (int hw = 0; hw < 36; hw++) gv = fmaf(act[ln * 37 + hw], sc[hw], gv);
    gm[ln] = gv;
  }
  __syncthreads();
  if (tid < 7) {
    float a = b3[tid];
    for (int c = 0; c < 64; c++) a = fmaf(w3[tid * 64 + c], gm[c], a);
    out[(size_t)(b0 + b) * 7 + tid] = a;
  }
}

// ============================================================================
extern "C" void kernel_launch(void* const* d_in, const int* in_sizes, int n_in,
                              void* d_out, int out_size, void* d_ws,
                              size_t ws_size, hipStream_t stream) {
  const float* x    = (const float*)d_in[0];
  const float* c1w  = (const float*)d_in[1];
  const float* c1b  = (const float*)d_in[2];
  const float* g1   = (const float*)d_in[3];
  const float* bb1  = (const float*)d_in[4];
  const float* m1   = (const float*)d_in[5];
  const float* v1   = (const float*)d_in[6];
  const float* c2w  = (const float*)d_in[7];
  const float* c2b  = (const float*)d_in[8];
  const float* g2   = (const float*)d_in[9];
  const float* bb2  = (const float*)d_in[10];
  const float* m2   = (const float*)d_in[11];
  const float* v2   = (const float*)d_in[12];
  const float* c3w  = (const float*)d_in[13];
  const float* c3b  = (const float*)d_in[14];
  const float* g3   = (const float*)d_in[15];
  const float* bb3  = (const float*)d_in[16];
  const float* m3   = (const float*)d_in[17];
  const float* v3   = (const float*)d_in[18];
  const float* fc1w = (const float*)d_in[19];
  const float* fc1b = (const float*)d_in[20];
  const float* fc2w = (const float*)d_in[21];
  const float* fc2b = (const float*)d_in[22];
  const float* attw = (const float*)d_in[23];
  const float* attb = (const float*)d_in[24];
  const float* fc3w = (const float*)d_in[25];
  const float* fc3b = (const float*)d_in[26];

  const size_t PER_CHUNK = (173056ULL + 25088ULL) * 2;  // bytes per image
  const size_t PERSIST = 589824 + 147456 + 131072 + 589824 + 256 + 8192;
  int CH = 512;
  while (CH > 8 && (size_t)CH * PER_CHUNK + PERSIST > ws_size) CH >>= 1;
  const int NCHK = 512 / CH;

  char* base = (char*)d_ws;
  size_t off = 0;
  auto alloc = [&](size_t nbytes) -> void* {
    void* p = base + off;
    off = (off + nbytes + 255) & ~(size_t)255;
    return p;
  };
  __hip_bfloat16* out1p = (__hip_bfloat16*)alloc((size_t)CH * 173056 * 2);
  __hip_bfloat16* out2p = (__hip_bfloat16*)alloc((size_t)CH * 25088 * 2);
  __hip_bfloat16* wt2  = (__hip_bfloat16*)alloc(589824);
  __hip_bfloat16* wt3  = (__hip_bfloat16*)alloc(147456);
  float* W32           = (float*)alloc(131072);
  float* Wet           = (float*)alloc(589824);
  float* be            = (float*)alloc(256);

  for (int c = 0; c < NCHK; c++) {
    const float* xc = x + (size_t)c * CH * 2304;
    const int nprep = (c == 0) ? 1569 : 0;   // weight prep fused in chunk 0
    k_conv1prep<<<nprep + CH * 4, 256, 0, stream>>>(
        xc, c1w, c1b, g1, bb1, m1, v1, out1p, out2p, c2w, wt2, c3w, wt3, attw,
        fc2w, W32, fc1b, fc2b, attb, be, nprep);
    const int n2 = CH * 6;
    const int grid2 = n2 + (c == 0 ? 576 : 0);  // W_eff fused in chunk 0
    k_mconv2<<<grid2, 256, 0, stream>>>(out1p, wt2, c2b, g2, bb2, m2, v2,
                                        out2p, W32, fc1w, Wet, n2);
    k_c3attn<<<CH, 256, 0, stream>>>(out2p, wt3, c3b, g3, bb3, m3, v3, Wet, be,
                                     fc3w, fc3b, (float*)d_out, c * CH);
  }
}

// Round 7
// 378.428 us; speedup vs baseline: 1.0691x; 1.0691x over previous
//
#include <hip/hip_runtime.h>
#include <hip/hip_bf16.h>
#include <math.h>

#define EPS_BN 1e-5f

typedef __bf16 bf16x8 __attribute__((ext_vector_type(8)));
typedef float f32x4 __attribute__((ext_vector_type(4)));
typedef float f32x2 __attribute__((ext_vector_type(2)));

// async global->LDS, 16B per lane. LDS dest must be wave-uniform base + lane*16
__device__ __forceinline__ void gl2lds16(const void* g, void* l) {
  __builtin_amdgcn_global_load_lds(
      (const __attribute__((address_space(1))) unsigned int*)g,
      (__attribute__((address_space(3))) unsigned int*)l, 16, 0, 0);
}

// ============================================================================
// R19 FUSED conv1 + weight-prep (one launch; all block ranges independent):
//   blocks [0,1152):            conv2 w -> bf16 [9][8][128][4][8]
//   blocks [1152,1440):         conv3 w -> bf16 [9][16][64][8]
//   blocks [1440,1504):         W_eff row r = blk-1440, SELF-CONTAINED:
//                               recompute W32 row (attw@fc2w) in LDS, then
//                               Wet[c][r] = W32row @ fc1w col c. (R18 showed
//                               W_eff under mconv2 poisons its L2: +33MB FETCH,
//                               +49us. Under VALU-bound conv1 it's free. Same
//                               fp32 accumulation order -> bit-identical.)
//   block  1504:                b_eff = att_w@(fc2_w@fc1_b + fc2_b) + att_b
//   blocks [nprep, nprep+CH*4): conv1 band path -> out1p bf16 NHWC [26][26][256]
// ============================================================================
__global__ __launch_bounds__(256) void k_conv1prep(
    const float* __restrict__ x, const float* __restrict__ w,
    const float* __restrict__ cb, const float* __restrict__ g,
    const float* __restrict__ bb, const float* __restrict__ m,
    const float* __restrict__ v, __hip_bfloat16* __restrict__ out1p,
    __hip_bfloat16* __restrict__ out2p, const float* __restrict__ c2w,
    __hip_bfloat16* __restrict__ wt2, const float* __restrict__ c3w,
    __hip_bfloat16* __restrict__ wt3, const float* __restrict__ attw,
    const float* __restrict__ fc2w, const float* __restrict__ fc1w,
    float* __restrict__ Wet, const float* __restrict__ fc1b,
    const float* __restrict__ fc2b, const float* __restrict__ attb,
    float* __restrict__ be, int nprep) {
  __shared__ float xp[14 * 50];  // conv1 input tile; aliased by prep paths
  const int blk = blockIdx.x;
  const int t = threadIdx.x;
  if (blk < nprep) {  // ---- weight prep paths (chunk 0 only) ----
    if (blk < 1152) {  // conv2 wt: [9][8][128][4][8]
      int idx = blk * 256 + t;
      int icr = idx & 7;
      int lhi = (idx >> 3) & 3;
      int oc = (idx >> 5) & 127;
      int rest = idx >> 12;
      int kb = rest & 7;
      int p = rest >> 3;
      int ic = kb * 32 + lhi * 8 + icr;
      wt2[idx] = __float2bfloat16(c2w[(oc * 256 + ic) * 9 + p]);
    } else if (blk < 1440) {  // conv3 wt: [9][16][64][8]
      int idx = (blk - 1152) * 256 + t;
      int icr = idx & 7;
      int oc = (idx >> 3) & 63;
      int rest = idx >> 9;
      int icg = rest & 15;
      int p = rest >> 4;
      wt3[idx] = __float2bfloat16(c3w[(oc * 128 + icg * 8 + icr) * 9 + p]);
    } else if (blk < 1504) {  // W_eff row r, self-contained
      float* w32row = xp;     // 512 floats, aliases xp (700 floats)
      const int r = blk - 1440;
      float a0 = 0.f, a1 = 0.f;
      for (int j = 0; j < 256; j++) {
        float aw = attw[r * 256 + j];
        a0 = fmaf(aw, fc2w[j * 512 + t], a0);
        a1 = fmaf(aw, fc2w[j * 512 + t + 256], a1);
      }
      w32row[t] = a0;
      w32row[t + 256] = a1;
      __syncthreads();
      float s[9];
#pragma unroll
      for (int i = 0; i < 9; i++) s[i] = 0.f;
      for (int k = 0; k < 512; k++) {
        float wv = w32row[k];
        const float* fr = fc1w + k * 2304 + t;
#pragma unroll
        for (int i = 0; i < 9; i++) s[i] = fmaf(wv, fr[i * 256], s[i]);
      }
#pragma unroll
      for (int i = 0; i < 9; i++) Wet[(i * 256 + t) * 64 + r] = s[i];
    } else {  // b_eff (t1 aliases xp's LDS)
      float* t1 = xp;
      float s = fc2b[t];
      for (int k = 0; k < 512; k++) s = fmaf(fc2w[t * 512 + k], fc1b[k], s);
      t1[t] = s;
      __syncthreads();
      if (t < 64) {
        float r = attb[t];
        for (int k = 0; k < 256; k++) r = fmaf(attw[t * 256 + k], t1[k], r);
        be[t] = r;
      }
    }
    return;
  }
  // ---- conv1 band path: band q covers output rows 6q..6q+5 ----
  const int bq = blk - nprep;
  const int b = bq >> 2, q = bq & 3;
  __hip_bfloat16* ob = out1p + (size_t)b * (26 * 26 * 256);
  const __hip_bfloat16 z = __float2bfloat16(0.f);
  if (q == 0)
    for (int i = t; i < 26 * 256; i += 256) ob[i] = z;
  if (q == 3)
    for (int i = t; i < 26 * 256; i += 256) ob[25 * 26 * 256 + i] = z;
  for (int i = t; i < 6 * 2 * 256; i += 256) {
    int r = 1 + 6 * q + (i >> 9), side = (i >> 8) & 1, c = i & 255;
    ob[(r * 26 + side * 25) * 256 + c] = z;
  }
  {
    __hip_bfloat16* o2 = out2p + (size_t)b * (14 * 14 * 128);
    if (q == 0)
      for (int i = t; i < 14 * 128; i += 256) o2[i] = z;
    if (q == 1)
      for (int i = t; i < 14 * 128; i += 256) o2[13 * 14 * 128 + i] = z;
    if (q == 2)
      for (int i = t; i < 6 * 2 * 128; i += 256) {
        int r = 1 + (i >> 8), side = (i >> 7) & 1, c = i & 127;
        o2[(r * 14 + side * 13) * 128 + c] = z;
      }
    if (q == 3)
      for (int i = t; i < 6 * 2 * 128; i += 256) {
        int r = 7 + (i >> 8), side = (i >> 7) & 1, c = i & 127;
        o2[(r * 14 + side * 13) * 128 + c] = z;
      }
  }
  for (int i = t; i < 14 * 50; i += 256) xp[i] = 0.f;
  __syncthreads();
  const float* xb = x + (size_t)b * 2304;
  for (int i = t; i < 14 * 48; i += 256) {
    int rr = i / 48, c = i - rr * 48;
    int gr = 12 * q - 1 + rr;
    if (gr >= 0 && gr < 48) xp[rr * 50 + c + 1] = xb[gr * 48 + c];
  }
  __syncthreads();
  float wr[9];
#pragma unroll
  for (int i = 0; i < 9; i++) wr[i] = w[t * 9 + i];
  const float scale = g[t] * rsqrtf(v[t] + EPS_BN);
  const float bias = (cb[t] - m[t]) * scale + bb[t];
#pragma unroll
  for (int ohl = 0; ohl < 6; ohl++) {
    const int r0 = 2 * ohl;
    f32x2 c01[4];
#pragma unroll
    for (int r = 0; r < 4; r++) c01[r] = *(const f32x2*)&xp[(r0 + r) * 50];
#pragma unroll 4
    for (int ow = 0; ow < 24; ow++) {
      f32x2 c23[4];
#pragma unroll
      for (int r = 0; r < 4; r++)
        c23[r] = *(const f32x2*)&xp[(r0 + r) * 50 + 2 * ow + 2];
      f32x2 s2a = 0.f, s2b = 0.f;  // dh = 0, 1 (packed over dw)
#pragma unroll
      for (int r = 0; r < 4; r++) {
        f32x2 p0 = c01[r], p2 = c23[r];
        f32x2 p1 = {p0.y, p2.x};
        if (r <= 2) {
          s2a += p0 * wr[r * 3 + 0];
          s2a += p1 * wr[r * 3 + 1];
          s2a += p2 * wr[r * 3 + 2];
        }
        if (r >= 1) {
          s2b += p0 * wr[(r - 1) * 3 + 0];
          s2b += p1 * wr[(r - 1) * 3 + 1];
          s2b += p2 * wr[(r - 1) * 3 + 2];
        }
      }
      f32x2 b0 = s2a * scale + bias;  // BN before pool
      f32x2 b1 = s2b * scale + bias;
      float mx = fmaxf(fmaxf(b0.x, b0.y), fmaxf(b1.x, b1.y));
      ob[((6 * q + ohl + 1) * 26 + (ow + 1)) * 256 + t] =
          __float2bfloat16(fmaxf(mx, 0.f));
#pragma unroll
      for (int r = 0; r < 4; r++) c01[r] = c23[r];
    }
  }
}

// ============================================================================
// conv2 MFMA implicit-GEMM + BN + ReLU + pool (bf16, fp32 acc).
// CLEAN again (R19): W_eff evicted back to conv1's launch — R18 proved its
// fc1w streaming (8 XCD x 4.7MB) poisons mconv2's weight L2 (+49us).
// Core = R17 measured best (146us, 57% of bf16 µbench ceiling): A-reg ring
// (dist 2), D=3 B-ring, precomputed A addrs (both ks variants), setprio
// around MFMA, 64-ic LDS dbuf via global_load_lds, late DMA (t=13),
// XCD swizzle.
// ============================================================================
__global__ __launch_bounds__(256) void k_mconv2(
    const __hip_bfloat16* __restrict__ in, const __hip_bfloat16* __restrict__ wt,
    const float* __restrict__ cb, const float* __restrict__ gg,
    const float* __restrict__ bbv, const float* __restrict__ bm,
    const float* __restrict__ bv, __hip_bfloat16* __restrict__ outp) {
  constexpr int HW = 24, IC = 256, OC = 128, HP = 26, CP = 26;
  constexpr int MTW = 6;            // m-frags per wave (all waves share M=96)
  constexpr int ROWS = 4;           // output h-rows per block
  constexpr int TILES = 6;          // blocks per image
  constexpr int WN = 32;            // wave N width
  constexpr int NF = 2;             // n-frags per wave
  constexpr int NCH = 6 * CP * 8;   // 1248 16B slots per window
  constexpr int NCHP = (NCH + 255) & ~255;  // 1280
  constexpr int NLD = NCHP / 256;   // 5
  constexpr int NSTG = 4;           // kc stages
  constexpr int ABUF = NCHP * 16;   // 20480 B per window
  constexpr int KG = IC / 32;       // 8
  constexpr int EPITCH = OC + 1;
  constexpr int EBYTES = 48 * EPITCH * 4;
  constexpr int SMB = (2 * ABUF) > EBYTES ? (2 * ABUF) : EBYTES;
  constexpr int NSTEP = NSTG * 18;  // 72
  constexpr int D = 3;              // B prefetch depth (register ring)
  constexpr int AD = 3;             // A prefetch ring depth

  __shared__ __align__(16) char smraw[SMB];
  float* se = (float*)smraw;

  const int tid = threadIdx.x;
  const int wn = tid >> 6, ln = tid & 63;
  const int lhi = ln >> 4, llo = ln & 15;

  // XCD-aware remap: all TILES tiles of an image on one XCD's L2.
  const int per = gridDim.x >> 3;
  const int xcd = blockIdx.x & 7, sl = blockIdx.x >> 3;
  const int b = xcd * (per / TILES) + sl / TILES;
  const int T = sl % TILES;
  const int h0 = T * ROWS;

  const __hip_bfloat16* inb = in + (size_t)b * HP * HP * IC;

  int srcoff[NLD];
#pragma unroll
  for (int i = 0; i < NLD; i++) {
    int ci = tid + i * 256;
    if (ci >= NCH) ci = NCH - 1;
    int kgslot = ci & 7;
    int rest = ci >> 3;
    int c = rest % CP;
    int r = rest / CP;
    int kg = kgslot ^ (c & 7);
    srcoff[i] = ((h0 + r) * HP + c) * IC + kg * 8;
  }
  // Loop-invariant A-fragment byte addrs, BOTH ks variants precomputed.
  // Full addr = abase[ks][mt%3][pw] + ph*3328 + (mt>=3)*6656 + (s&1)*20480
  // (trailing terms are compile-time imm under full unroll).
  int abase[2][3][3];
#pragma unroll
  for (int mt = 0; mt < 3; mt++) {
    int m = mt * 16 + llo;
    int hl = m / HW, wl = m % HW;
    int spb_ = (hl * CP + wl) * 8;
#pragma unroll
    for (int pw = 0; pw < 3; pw++) {
      int a0 = (spb_ + pw * 8 + (lhi ^ ((wl + pw) & 7))) * 16;
      abase[0][mt][pw] = a0;
      abase[1][mt][pw] = a0 ^ 64;  // kg bit2 -> byte addr bit6, carry-free
    }
  }
  const __hip_bfloat16* wtb = wt + (wn * WN + llo) * 32 + lhi * 8;

  f32x4 acc[MTW][NF];
  const f32x4 fz = {0.f, 0.f, 0.f, 0.f};
#pragma unroll
  for (int i = 0; i < MTW; i++)
#pragma unroll
    for (int j = 0; j < NF; j++) acc[i][j] = fz;

  // A-fragment loader for step t of window s (s,t compile-time const under
  // full unroll -> static aq indices + imm ds offsets, no scratch).
  auto LDA = [&](int s, int t, bf16x8* dst) {
    const int p = t >> 1, ks = t & 1;
    const int ph = p / 3, pw = p % 3;
    const int boff = ph * 3328 + ((s & 1) ? ABUF : 0);
#pragma unroll
    for (int mt = 0; mt < MTW; mt++) {
      dst[mt] = *(const bf16x8*)(smraw + abase[ks][mt % 3][pw] + boff +
                                 (mt >= 3 ? 6656 : 0));
    }
  };

  // prologue: DMA stage 0 into window 0; preload B ring for steps 0..D-1
#pragma unroll
  for (int i = 0; i < NLD; i++)
    gl2lds16(inb + srcoff[i], smraw + (tid + i * 256) * 16);
  bf16x8 bq[D][NF];
#pragma unroll
  for (int d = 0; d < D; d++) {
    const int sg = d / 18, pg = (d % 18) >> 1, kf = d & 1;
#pragma unroll
    for (int j = 0; j < NF; j++)
      bq[d][j] = *(const bf16x8*)(wtb +
                                  (size_t)((pg * KG + sg * 2 + kf) * OC) * 32 +
                                  j * 512);
  }
  __syncthreads();

#pragma unroll
  for (int s = 0; s < NSTG; s++) {
    bf16x8 aq[AD][MTW];  // A register ring
    LDA(s, 0, aq[0]);
    LDA(s, 1, aq[1]);
#pragma unroll
    for (int t = 0; t < 18; t++) {
      const int g = s * 18 + t;
      // prefetch step t+2's A frags before this step's MFMAs
      if (t + 2 < 18) LDA(s, t + 2, aq[(t + 2) % AD]);
      // consume aq[t%AD] x bq[g%D]; setprio favors MFMA-entering waves
      __builtin_amdgcn_s_setprio(1);
#pragma unroll
      for (int mt = 0; mt < MTW; mt++)
#pragma unroll
        for (int j = 0; j < NF; j++)
          acc[mt][j] = __builtin_amdgcn_mfma_f32_16x16x32_bf16(
              aq[t % AD][mt], bq[g % D][j], acc[mt][j], 0, 0, 0);
      __builtin_amdgcn_s_setprio(0);
      // refill B ring slot for step g+D (after consume: WAR on ring slot)
      if (g + D < NSTEP) {
        const int gf = g + D;
        const int sg = gf / 18, pg = (gf % 18) >> 1, kf = gf & 1;
#pragma unroll
        for (int j = 0; j < NF; j++)
          bq[gf % D][j] =
              *(const bf16x8*)(wtb +
                               (size_t)((pg * KG + sg * 2 + kf) * OC) * 32 +
                               j * 512);
      }
      // issue next-window DMA LATE (after this step's ring refill)
      if (t == 13 && s + 1 < NSTG) {
        char* nb = smraw + ((s + 1) & 1) * ABUF;
#pragma unroll
        for (int i = 0; i < NLD; i++)
          gl2lds16(inb + srcoff[i] + (s + 1) * 64, nb + (tid + i * 256) * 16);
      }
    }
    __syncthreads();  // window s reads done; DMA for s+1 drained
  }

  // ---- epilogue in 48-row passes: BN+ReLU -> se [48][129], pool, store
  constexpr int OHW = HW / 2;
  constexpr int NP = 1 * OHW * OC;  // pooled rows per pass = 1
#pragma unroll
  for (int pz = 0; pz < 2; pz++) {
    if (pz) __syncthreads();
#pragma unroll
    for (int j = 0; j < NF; j++) {
      int n = wn * WN + j * 16 + llo;
      float scale = gg[n] * rsqrtf(bv[n] + EPS_BN);
      float bias = (cb[n] - bm[n]) * scale + bbv[n];
#pragma unroll
      for (int mtl = 0; mtl < 3; mtl++)
#pragma unroll
        for (int r = 0; r < 4; r++) {
          int mrow = mtl * 16 + lhi * 4 + r;
          se[mrow * EPITCH + n] =
              fmaxf(acc[pz * 3 + mtl][j][r] * scale + bias, 0.f);
        }
    }
    __syncthreads();
    for (int sI = tid; sI < NP; sI += 256) {
      int n = sI % OC;
      int ow = (sI / OC) % OHW;
      int mloc = 2 * ow;
      float x0 = se[mloc * EPITCH + n];
      float x1 = se[(mloc + 1) * EPITCH + n];
      float x2 = se[(mloc + HW) * EPITCH + n];
      float x3 = se[(mloc + HW + 1) * EPITCH + n];
      float mx = fmaxf(fmaxf(x0, x1), fmaxf(x2, x3));
      int oh = (h0 >> 1) + pz;
      // padded bf16 NHWC [14][14][128], interior at +1
      outp[(((size_t)b * 14 + oh + 1) * 14 + ow + 1) * OC + n] =
          __float2bfloat16(mx);
    }
  }
}

// ============================================================================
// FUSED conv3 + BN + ReLU + pool + spatial attention + fc3. One block/image.
// (unchanged — measured good)
// ============================================================================
__global__ __launch_bounds__(256) void k_c3attn(
    const __hip_bfloat16* __restrict__ in, const __hip_bfloat16* __restrict__ wt,
    const float* __restrict__ cb, const float* __restrict__ gg,
    const float* __restrict__ bbv, const float* __restrict__ bm,
    const float* __restrict__ bv, const float* __restrict__ Wet,
    const float* __restrict__ be, const float* __restrict__ w3,
    const float* __restrict__ b3, float* __restrict__ out, int b0) {
  constexpr int HW = 12, IC = 128, OC = 64, HP = 14, CP = 14;
  constexpr int NCH = 14 * CP * 8;
  constexpr int NCHP = (NCH + 255) & ~255;
  constexpr int NLD = NCHP / 256;
  constexpr int NSTG = 2;
  constexpr int ABUF = NCHP * 16;
  constexpr int ICG = 16;
  constexpr int EPITCH = OC + 1;

  __shared__ __align__(16) char smraw[2 * ABUF];
  __shared__ float act[64 * 37];
  __shared__ float qp[4][64];
  __shared__ float ql[64], gm[64], sc[36];
  float* se = (float*)smraw;

  const int tid = threadIdx.x;
  const int wv = tid >> 6, ln = tid & 63;
  const int lhi = ln >> 4, llo = ln & 15;
  const int b = blockIdx.x;

  const __hip_bfloat16* inb = in + (size_t)b * HP * HP * IC;

  int srcoff[NLD];
#pragma unroll
  for (int i = 0; i < NLD; i++) {
    int ci = tid + i * 256;
    if (ci >= NCH) ci = NCH - 1;
    int kgslot = ci & 7;
    int rest = ci >> 3;
    int c = rest % CP;
    int r = rest / CP;
    int kg = kgslot ^ (c & 7);
    srcoff[i] = (r * HP + c) * IC + kg * 8;
  }
  int spb[9], wlv[9];
#pragma unroll
  for (int mt = 0; mt < 9; mt++) {
    int m = mt * 16 + llo;
    int hl = m / HW, wl = m % HW;
    spb[mt] = (hl * CP + wl) * 8;
    wlv[mt] = wl;
  }
  const __hip_bfloat16* wtb = wt + (size_t)(lhi * OC + wv * 16 + llo) * 8;

  f32x4 acc[9];
  const f32x4 fz = {0.f, 0.f, 0.f, 0.f};
#pragma unroll
  for (int i = 0; i < 9; i++) acc[i] = fz;

#pragma unroll
  for (int i = 0; i < NLD; i++)
    gl2lds16(inb + srcoff[i], smraw + (tid + i * 256) * 16);
  __syncthreads();

#pragma unroll
  for (int s = 0; s < NSTG; s++) {
    if (s + 1 < NSTG) {
      char* nb = smraw + ((s + 1) & 1) * ABUF;
#pragma unroll
      for (int i = 0; i < NLD; i++)
        gl2lds16(inb + srcoff[i] + (s + 1) * 64, nb + (tid + i * 256) * 16);
    }
    const char* cw = smraw + (s & 1) * ABUF;
#pragma unroll
    for (int tt = 0; tt < 18; tt++) {
      const int p = tt >> 1, ks = tt & 1;
      const int ph = p / 3, pw = p % 3;
      const int kg = ks * 4 + lhi;
      bf16x8 bf =
          *(const bf16x8*)(wtb + ((size_t)(p * ICG + s * 8 + ks * 4) * OC) * 8);
#pragma unroll
      for (int mt = 0; mt < 9; mt++) {
        int slot = spb[mt] + (ph * CP + pw) * 8 + (kg ^ ((wlv[mt] + pw) & 7));
        bf16x8 af = *(const bf16x8*)(cw + slot * 16);
        acc[mt] = __builtin_amdgcn_mfma_f32_16x16x32_bf16(af, bf, acc[mt], 0,
                                                          0, 0);
      }
    }
    __syncthreads();
  }

  {
    const int n = wv * 16 + llo;
    const float scale = gg[n] * rsqrtf(bv[n] + EPS_BN);
    const float bias = (cb[n] - bm[n]) * scale + bbv[n];
#pragma unroll
    for (int pz = 0; pz < 3; pz++) {
      if (pz) __syncthreads();
#pragma unroll
      for (int mtl = 0; mtl < 3; mtl++)
#pragma unroll
        for (int r = 0; r < 4; r++) {
          int mrow = mtl * 16 + lhi * 4 + r;
          se[mrow * EPITCH + n] =
              fmaxf(acc[pz * 3 + mtl][r] * scale + bias, 0.f);
        }
      __syncthreads();
      for (int sI = tid; sI < 2 * 6 * 64; sI += 256) {
        int nn = sI % 64;
        int ow = (sI / 64) % 6;
        int ohl = sI / (64 * 6);
        int mloc = (2 * ohl) * HW + 2 * ow;
        float x0 = se[mloc * EPITCH + nn];
        float x1 = se[(mloc + 1) * EPITCH + nn];
        float x2 = se[(mloc + HW) * EPITCH + nn];
        float x3 = se[(mloc + HW + 1) * EPITCH + nn];
        float mx = fmaxf(fmaxf(x0, x1), fmaxf(x2, x3));
        act[nn * 37 + (pz * 2 + ohl) * 6 + ow] = mx;
      }
    }
  }
  __syncthreads();

  {
    float qpv = 0.f;
    const int n = ln;
#pragma unroll 2
    for (int c2 = wv * 16; c2 < wv * 16 + 16; c2++)
      for (int hw = 0; hw < 36; hw++)
        qpv = fmaf(act[c2 * 37 + hw], Wet[(c2 * 36 + hw) * 64 + n], qpv);
    qp[wv][n] = qpv;
  }
  __syncthreads();
  if (tid < 64)
    ql[tid] = be[tid] + qp[0][tid] + qp[1][tid] + qp[2][tid] + qp[3][tid];
  __syncthreads();
  if (wv == 0) {
    float s = -INFINITY;
    if (ln < 36) {
      float a = 0.f;
      for (int c = 0; c < 64; c++) a = fmaf(act[c * 37 + ln], ql[c], a);
      s = a;
    }
    float mx = s;
    for (int off = 32; off >= 1; off >>= 1)
      mx = fmaxf(mx, __shfl_xor(mx, off));
    float e = (ln < 36) ? expf(s - mx) : 0.f;
    float sum = e;
    for (int off = 32; off >= 1; off >>= 1) sum += __shfl_xor(sum, off);
    if (ln < 36) sc[ln] = e / sum;
  }
  __syncthreads();
  if (wv == 0) {
    float gv = 0.f;
    for (int hw = 0; hw < 36; hw++) gv = fmaf(act[ln * 37 + hw], sc[hw], gv);
    gm[ln] = gv;
  }
  __syncthreads();
  if (tid < 7) {
    float a = b3[tid];
    for (int c = 0; c < 64; c++) a = fmaf(w3[tid * 64 + c], gm[c], a);
    out[(size_t)(b0 + b) * 7 + tid] = a;
  }
}

// ============================================================================
extern "C" void kernel_launch(void* const* d_in, const int* in_sizes, int n_in,
                              void* d_out, int out_size, void* d_ws,
                              size_t ws_size, hipStream_t stream) {
  const float* x    = (const float*)d_in[0];
  const float* c1w  = (const float*)d_in[1];
  const float* c1b  = (const float*)d_in[2];
  const float* g1   = (const float*)d_in[3];
  const float* bb1  = (const float*)d_in[4];
  const float* m1   = (const float*)d_in[5];
  const float* v1   = (const float*)d_in[6];
  const float* c2w  = (const float*)d_in[7];
  const float* c2b  = (const float*)d_in[8];
  const float* g2   = (const float*)d_in[9];
  const float* bb2  = (const float*)d_in[10];
  const float* m2   = (const float*)d_in[11];
  const float* v2   = (const float*)d_in[12];
  const float* c3w  = (const float*)d_in[13];
  const float* c3b  = (const float*)d_in[14];
  const float* g3   = (const float*)d_in[15];
  const float* bb3  = (const float*)d_in[16];
  const float* m3   = (const float*)d_in[17];
  const float* v3   = (const float*)d_in[18];
  const float* fc1w = (const float*)d_in[19];
  const float* fc1b = (const float*)d_in[20];
  const float* fc2w = (const float*)d_in[21];
  const float* fc2b = (const float*)d_in[22];
  const float* attw = (const float*)d_in[23];
  const float* attb = (const float*)d_in[24];
  const float* fc3w = (const float*)d_in[25];
  const float* fc3b = (const float*)d_in[26];

  const size_t PER_CHUNK = (173056ULL + 25088ULL) * 2;  // bytes per image
  const size_t PERSIST = 589824 + 147456 + 589824 + 256 + 8192;
  int CH = 512;
  while (CH > 8 && (size_t)CH * PER_CHUNK + PERSIST > ws_size) CH >>= 1;
  const int NCHK = 512 / CH;

  char* base = (char*)d_ws;
  size_t off = 0;
  auto alloc = [&](size_t nbytes) -> void* {
    void* p = base + off;
    off = (off + nbytes + 255) & ~(size_t)255;
    return p;
  };
  __hip_bfloat16* out1p = (__hip_bfloat16*)alloc((size_t)CH * 173056 * 2);
  __hip_bfloat16* out2p = (__hip_bfloat16*)alloc((size_t)CH * 25088 * 2);
  __hip_bfloat16* wt2  = (__hip_bfloat16*)alloc(589824);
  __hip_bfloat16* wt3  = (__hip_bfloat16*)alloc(147456);
  float* Wet           = (float*)alloc(589824);
  float* be            = (float*)alloc(256);

  for (int c = 0; c < NCHK; c++) {
    const float* xc = x + (size_t)c * CH * 2304;
    const int nprep = (c == 0) ? 1505 : 0;   // weight prep fused in chunk 0
    k_conv1prep<<<nprep + CH * 4, 256, 0, stream>>>(
        xc, c1w, c1b, g1, bb1, m1, v1, out1p, out2p, c2w, wt2, c3w, wt3, attw,
        fc2w, fc1w, Wet, fc1b, fc2b, attb, be, nprep);
    k_mconv2<<<CH * 6, 256, 0, stream>>>(out1p, wt2, c2b, g2, bb2, m2, v2,
                                         out2p);
    k_c3attn<<<CH, 256, 0, stream>>>(out2p, wt3, c3b, g3, bb3, m3, v3, Wet, be,
                                     fc3w, fc3b, (float*)d_out, c * CH);
  }
}